// Round 14
// baseline (225.515 us; speedup 1.0000x reference)
//
#include <hip/hip_runtime.h>
#include <hip/hip_bf16.h>

// GraphConv 2-hop: gather(ent[tail]*rel[type]) -> scatter-mean by head -> l2norm,
// twice, fused residual outputs.
//
// R2->R3: atomic scatter -> bucket counting sort: 360->251us.
// R4->R6: bf16 gather table: hops 74->57us. R6->R8: pair-edge hop: 57->54.3us.
// R9: cooperative grid.sync CSR: REGRESSED 275us. Reverted.
// R13: sync-free fusions (6 launches): only -1.5us => launch gaps ~0.5us each.
//      Time model: ~75us fixed harness + 104us hops + ~40us CSR.
// R14: (a) hop 4-edges/instr (16 lanes x uint2/edge, float4 rel broadcast);
//      (b) CHUNK 4096 (306 chunks -> full CU coverage in place/hist) via
//          2-elem/thread scan (2048/block keeps nscan=59<=64 for pref mini-scan).
//
// ws (ints): packed[E] | unionA{staging int[E], ent1 u16[n_ent*64]} |
//            ent_bf16 u16[n_ent*64] | G[L] | Gscan[L] | bsum[128] |
//            row_start[n_ent+1] | rel1 f32[n_rel*64]
// unionA safe: staging dies at finalize; ent1 born in hop1 (after finalize).

#define CHUNK 4096
#define BSHIFT 8
#define BMASK 255

__device__ __forceinline__ float b2f(unsigned int u16bits) {
    return __uint_as_float(u16bits << 16);
}
__device__ __forceinline__ unsigned int f2b_u32(float f) {  // bf16 bits, RNE
    unsigned int u = __float_as_uint(f);
    return (u + 0x7FFFu + ((u >> 16) & 1u)) >> 16;
}

// ---- K1: blocks [0,nchunks): per-chunk bucket histogram; rest: cvt; last: +rel ----
__global__ __launch_bounds__(512) void fused_pre_kernel(
    const int* __restrict__ heads, const float* __restrict__ entity_emb,
    const float* __restrict__ relation_emb,
    int* __restrict__ G, unsigned int* __restrict__ ent_bf16,
    float* __restrict__ rel1, float* __restrict__ out_rel,
    int E, int nchunks, int nb, int n_ent, int n_rel, int preb)
{
    const int b = blockIdx.x;
    const int tid = threadIdx.x;
    if (b < nchunks) {
        __shared__ int hist[512];
        for (int i = tid; i < nb; i += 512) hist[i] = 0;
        __syncthreads();
        const int lo = b * CHUNK;
        const int hi = min(lo + CHUNK, E);
        for (int i = lo + tid; i < hi; i += 512)
            atomicAdd(&hist[heads[i] >> BSHIFT], 1);
        __syncthreads();
        for (int i = tid; i < nb; i += 512) G[i * nchunks + b] = hist[i];
    } else {
        const int lane = tid & 63;
        const int w = tid >> 6;
        if (b == preb - 1) {
            // rel1 = l2norm(rel0); rel2 = l2norm(rel1) (= rel1); out = rel0+rel1+rel2
            for (int row = w; row < n_rel; row += 8) {
                float v = relation_emb[row * 64 + lane];
                float ss = v * v;
#pragma unroll
                for (int off = 32; off > 0; off >>= 1) ss += __shfl_xor(ss, off);
                float r1v = v / fmaxf(sqrtf(ss), 1e-12f);
                float ss2 = r1v * r1v;
#pragma unroll
                for (int off = 32; off > 0; off >>= 1) ss2 += __shfl_xor(ss2, off);
                float r2v = r1v / fmaxf(sqrtf(ss2), 1e-12f);
                rel1[row * 64 + lane] = r1v;
                out_rel[row * 64 + lane] = v + r1v + r2v;
            }
        }
        const int ncvt = preb - nchunks;
        const int cb = b - nchunks;
        const int n4 = n_ent * 16;
        const uint4* in4 = (const uint4*)entity_emb;
        uint2* out2 = (uint2*)ent_bf16;
        for (int i = cb * 512 + tid; i < n4; i += ncvt * 512) {
            uint4 v = in4[i];
            uint2 o;
            o.x = f2b_u32(__uint_as_float(v.x)) | (f2b_u32(__uint_as_float(v.y)) << 16);
            o.y = f2b_u32(__uint_as_float(v.z)) | (f2b_u32(__uint_as_float(v.w)) << 16);
            out2[i] = o;
        }
    }
}

// ---- K2: exclusive scan of G, 2048 elems/block (2 per thread); totals to bsum ----
__global__ void scan_block(const int* __restrict__ in, int* __restrict__ out_excl,
                           int* __restrict__ blocksum, int n) {
    __shared__ int wsum[16];
    const int tid = threadIdx.x;                 // 1024
    const int gi = blockIdx.x * 2048 + tid * 2;
    const int lane = tid & 63, wid = tid >> 6;
    int v0 = (gi < n) ? in[gi] : 0;
    int v1 = (gi + 1 < n) ? in[gi + 1] : 0;
    int t = v0 + v1;
    int s = t;
#pragma unroll
    for (int off = 1; off < 64; off <<= 1) {
        int u = __shfl_up(s, off);
        if (lane >= off) s += u;
    }
    if (lane == 63) wsum[wid] = s;
    __syncthreads();
    if (wid == 0) {
        int ws = (lane < 16) ? wsum[lane] : 0;
#pragma unroll
        for (int off = 1; off < 16; off <<= 1) {
            int u = __shfl_up(ws, off);
            if (lane >= off) ws += u;
        }
        if (lane < 16) wsum[lane] = ws;
        if (lane == 15 && blocksum) blocksum[blockIdx.x] = ws;
    }
    __syncthreads();
    int woff = (wid > 0) ? wsum[wid - 1] : 0;
    int excl = s - t + woff;
    if (gi < n) out_excl[gi] = excl;
    if (gi + 1 < n) out_excl[gi + 1] = excl + v0;
}

// ---- K3: place edges into per-(chunk,bucket) disjoint staging ranges ----
// bsum prefix computed in-block by wave 0 (nscan<=64 entries; scan chunk=2048).
__global__ __launch_bounds__(512) void place_stage_kernel(
    const int* __restrict__ heads, const int* __restrict__ tails,
    const int* __restrict__ etype, const int* __restrict__ Gscan,
    const int* __restrict__ bsum,
    int* __restrict__ staging, int E, int nchunks, int nb, int nscan)
{
    __shared__ int cur[512];
    __shared__ int pref[64];
    const int blk = blockIdx.x;
    const int tid = threadIdx.x;
    if (tid < 64) {
        int v = (tid < nscan) ? bsum[tid] : 0;
        int s = v;
#pragma unroll
        for (int off = 1; off < 64; off <<= 1) {
            int t = __shfl_up(s, off);
            if (tid >= off) s += t;
        }
        pref[tid] = s - v;   // exclusive
    }
    __syncthreads();
    for (int i = tid; i < nb; i += 512) {
        int idx = i * nchunks + blk;
        cur[i] = Gscan[idx] + pref[idx >> 11];
    }
    __syncthreads();
    const int lo = blk * CHUNK;
    const int hi = min(lo + CHUNK, E);
    for (int i = lo + tid; i < hi; i += 512) {
        int h = heads[i];
        int entry = tails[i] | (etype[i] << 17) | ((h & BMASK) << 21);
        int pos = atomicAdd(&cur[h >> BSHIFT], 1);
        staging[pos] = entry;
    }
}

// ---- K4: per-bucket degree count + scan -> row_start; final CSR placement ----
__global__ __launch_bounds__(512) void finalize_kernel(
    const int* __restrict__ staging, const int* __restrict__ Gscan,
    const int* __restrict__ bsum,
    int* __restrict__ packed, int* __restrict__ row_start,
    int E, int nchunks, int nb, int nscan, int n_ent)
{
    __shared__ int deg[256], pos[256], cur[256];
    __shared__ int pref[64];
    const int b = blockIdx.x;
    const int tid = threadIdx.x;              // 512 threads
    if (tid < 64) {
        int v = (tid < nscan) ? bsum[tid] : 0;
        int s = v;
#pragma unroll
        for (int off = 1; off < 64; off <<= 1) {
            int t = __shfl_up(s, off);
            if (tid >= off) s += t;
        }
        pref[tid] = s - v;
    }
    __syncthreads();
    const int head_lo = b << BSHIFT;
    const int i0 = b * nchunks;
    const int seg_start = Gscan[i0] + pref[i0 >> 11];
    int seg_end = E;
    if (b + 1 < nb) {
        const int i1 = (b + 1) * nchunks;
        seg_end = Gscan[i1] + pref[i1 >> 11];
    }
    if (tid < 256) deg[tid] = 0;
    __syncthreads();
    for (int i = seg_start + tid; i < seg_end; i += 512)
        atomicAdd(&deg[(staging[i] >> 21) & BMASK], 1);
    __syncthreads();
    if (tid < 256) pos[tid] = deg[tid];
    __syncthreads();
    for (int off = 1; off < 256; off <<= 1) {
        int t = (tid >= off && tid < 256) ? pos[tid - off] : 0;
        __syncthreads();
        if (tid < 256) pos[tid] += t;
        __syncthreads();
    }
    if (tid < 256) {
        const int excl = pos[tid] - deg[tid];
        const int h = head_lo + tid;
        if (h < n_ent) row_start[h] = seg_start + excl;
        cur[tid] = seg_start + excl;
    }
    if (b == 0 && tid == 0) row_start[n_ent] = E;
    __syncthreads();
    for (int i = seg_start + tid; i < seg_end; i += 512) {
        int v = staging[i];
        int p = atomicAdd(&cur[(v >> 21) & BMASK], 1);
        packed[p] = v;
    }
}

// ---- hop: one wave per row; 4 quarters x 16 lanes; each lane: uint2 = 4 bf16
//      channels of one edge => 4 edges per wave-instruction; f32 accumulation ----
template <bool FINAL>
__global__ void hop_kernel(const uint2* __restrict__ ent_src,   // bf16 table (4ch/uint2)
                           const float* __restrict__ rel_src,
                           const int* __restrict__ row_start,
                           const int* __restrict__ packed,
                           uint2* __restrict__ ent_next,        // FINAL=false
                           const float4* __restrict__ ent0,     // FINAL=true
                           const float4* __restrict__ drug0,    // FINAL=true
                           float4* __restrict__ out_ent,        // FINAL=true
                           float4* __restrict__ out_drug,       // FINAL=true
                           int n_rows, int n_drugs) {
    __shared__ float rel_lds[16 * 64];
    for (int i = threadIdx.x; i < 16 * 64; i += blockDim.x) rel_lds[i] = rel_src[i];
    __syncthreads();

    const int lane = threadIdx.x & 63;
    const int q = lane >> 4;                  // edge-slot quarter 0..3
    const int c4 = lane & 15;                 // channel quad: channels 4c4..4c4+3
    const int wave = blockIdx.x * (blockDim.x >> 6) + (threadIdx.x >> 6);
    const int nw = gridDim.x * (blockDim.x >> 6);

    for (int r = wave; r < n_rows; r += nw) {
        const int start = row_start[r];
        const int deg = row_start[r + 1] - start;
        float4 acc0 = make_float4(0.f, 0.f, 0.f, 0.f);
        float4 acc1 = make_float4(0.f, 0.f, 0.f, 0.f);
        for (int base = 0; base < deg; base += 64) {
            int rem = deg - base;
            if (rem > 64) rem = 64;
            int pk = 0;
            if (lane < rem) pk = packed[start + base + lane];
            const int nquads = (rem + 3) >> 2;
            for (int i = 0; i < nquads; i += 2) {
                int e0 = 4 * i + q;
                int e1 = 4 * (i + 1) + q;
                int p0 = __shfl(pk, e0 & 63);
                int p1 = __shfl(pk, e1 & 63);
                uint2 u0 = make_uint2(0u, 0u), u1 = make_uint2(0u, 0u);
                if (e0 < rem) u0 = ent_src[(size_t)(p0 & 131071) * 16 + c4];
                if (e1 < rem) u1 = ent_src[(size_t)(p1 & 131071) * 16 + c4];
                const float4 r0 = *(const float4*)&rel_lds[((p0 >> 17) & 15) * 64 + 4 * c4];
                const float4 r1 = *(const float4*)&rel_lds[((p1 >> 17) & 15) * 64 + 4 * c4];
                acc0.x = fmaf(b2f(u0.x & 0xFFFFu), r0.x, acc0.x);
                acc0.y = fmaf(b2f(u0.x >> 16),     r0.y, acc0.y);
                acc0.z = fmaf(b2f(u0.y & 0xFFFFu), r0.z, acc0.z);
                acc0.w = fmaf(b2f(u0.y >> 16),     r0.w, acc0.w);
                acc1.x = fmaf(b2f(u1.x & 0xFFFFu), r1.x, acc1.x);
                acc1.y = fmaf(b2f(u1.x >> 16),     r1.y, acc1.y);
                acc1.z = fmaf(b2f(u1.y & 0xFFFFu), r1.z, acc1.z);
                acc1.w = fmaf(b2f(u1.y >> 16),     r1.w, acc1.w);
            }
        }
        float4 a;
        a.x = acc0.x + acc1.x;
        a.y = acc0.y + acc1.y;
        a.z = acc0.z + acc1.z;
        a.w = acc0.w + acc1.w;
        // combine the 4 edge-slot quarters (lanes sharing c4)
        a.x += __shfl_xor(a.x, 16); a.x += __shfl_xor(a.x, 32);
        a.y += __shfl_xor(a.y, 16); a.y += __shfl_xor(a.y, 32);
        a.z += __shfl_xor(a.z, 16); a.z += __shfl_xor(a.z, 32);
        a.w += __shfl_xor(a.w, 16); a.w += __shfl_xor(a.w, 32);
        const float denom = (float)(deg > 0 ? deg : 1);
        a.x /= denom; a.y /= denom; a.z /= denom; a.w /= denom;
        float ss = a.x * a.x + a.y * a.y + a.z * a.z + a.w * a.w;
#pragma unroll
        for (int off = 8; off > 0; off >>= 1) ss += __shfl_xor(ss, off);
        const float inv = 1.0f / fmaxf(sqrtf(ss), 1e-12f);
        const float e2x = a.x * inv, e2y = a.y * inv, e2z = a.z * inv, e2w = a.w * inv;
        if (!FINAL) {
            if (q == 0) {
                uint2 o;
                o.x = f2b_u32(e2x) | (f2b_u32(e2y) << 16);
                o.y = f2b_u32(e2z) | (f2b_u32(e2w) << 16);
                ent_next[(size_t)r * 16 + c4] = o;
            }
        } else {
            if (q == 0) {
                const uint2 e1u = ent_src[(size_t)r * 16 + c4];   // ent1 row (bf16)
                const float s0 = b2f(e1u.x & 0xFFFFu) + e2x;
                const float s1 = b2f(e1u.x >> 16) + e2y;
                const float s2 = b2f(e1u.y & 0xFFFFu) + e2z;
                const float s3 = b2f(e1u.y >> 16) + e2w;
                const float4 b0 = ent0[(size_t)r * 16 + c4];
                float4 o;
                o.x = b0.x + s0; o.y = b0.y + s1; o.z = b0.z + s2; o.w = b0.w + s3;
                out_ent[(size_t)r * 16 + c4] = o;
                if (r < n_drugs) {
                    const float4 bd = drug0[(size_t)r * 16 + c4];
                    float4 od;
                    od.x = bd.x + s0; od.y = bd.y + s1; od.z = bd.z + s2; od.w = bd.w + s3;
                    out_drug[(size_t)r * 16 + c4] = od;
                }
            }
        }
    }
}

extern "C" void kernel_launch(void* const* d_in, const int* in_sizes, int n_in,
                              void* d_out, int out_size, void* d_ws, size_t ws_size,
                              hipStream_t stream) {
    const float* drug_emb = (const float*)d_in[0];
    const float* entity_emb = (const float*)d_in[1];
    const float* relation_emb = (const float*)d_in[2];
    const int* edge_index = (const int*)d_in[3];
    const int* edge_type = (const int*)d_in[4];

    const int n_drugs = in_sizes[0] / 64;   // 2000
    const int n_ent = in_sizes[1] / 64;     // 100000
    const int n_rel = in_sizes[2] / 64;     // 16
    const int E = in_sizes[4];              // 1250000

    const int* heads = edge_index;
    const int* tails = edge_index + E;

    const int nchunks = (E + CHUNK - 1) / CHUNK;          // 306
    const int nb = (n_ent + (1 << BSHIFT) - 1) >> BSHIFT; // 391
    const int L = nb * nchunks;                           // 119,646
    const int nscan = (L + 2047) / 2048;                  // 59 (<=64)
    const int preb = nchunks + 360;                       // 666 blocks

    // ws carve-up (int units).
    int* packed = (int*)d_ws;                                    // E
    int* unionA = packed + ((E + 1) & ~1);                       // staging | ent1
    int* staging = unionA;                                       // E (dies at finalize)
    uint2* ent1 = (uint2*)unionA;                                // n_ent*16 uint2
    size_t unionA_ints = (size_t)n_ent * 32;                     // 3.2M >= E
    if (unionA_ints < (size_t)E) unionA_ints = (size_t)E;
    unsigned int* ent_bf16 = (unsigned int*)(unionA + unionA_ints);  // n_ent*32
    int* G = unionA + unionA_ints + (size_t)n_ent * 32;          // L
    int* Gscan = G + L;                                          // L
    int* bsum = Gscan + L;                                       // 128
    int* row_start = bsum + 128;                                 // n_ent+1
    float* rel1 = (float*)(row_start + n_ent + 1);               // n_rel*64

    float* out_ent = (float*)d_out;
    float* out_drug = out_ent + (size_t)n_ent * 64;
    float* out_rel = out_drug + (size_t)n_drugs * 64;

    fused_pre_kernel<<<preb, 512, 0, stream>>>(heads, entity_emb, relation_emb,
                                               G, ent_bf16, rel1, out_rel,
                                               E, nchunks, nb, n_ent, n_rel, preb);
    scan_block<<<nscan, 1024, 0, stream>>>(G, Gscan, bsum, L);
    place_stage_kernel<<<nchunks, 512, 0, stream>>>(heads, tails, edge_type, Gscan,
                                                    bsum, staging, E, nchunks, nb, nscan);
    finalize_kernel<<<nb, 512, 0, stream>>>(staging, Gscan, bsum, packed, row_start,
                                            E, nchunks, nb, nscan, n_ent);
    hop_kernel<false><<<2048, 256, 0, stream>>>((const uint2*)ent_bf16, relation_emb,
                                                row_start, packed, ent1,
                                                nullptr, nullptr, nullptr, nullptr,
                                                n_ent, 0);
    hop_kernel<true><<<2048, 256, 0, stream>>>((const uint2*)ent1, rel1, row_start, packed,
                                               nullptr, (const float4*)entity_emb,
                                               (const float4*)drug_emb,
                                               (float4*)out_ent, (float4*)out_drug,
                                               n_ent, n_drugs);
}

// Round 15
// 220.602 us; speedup vs baseline: 1.0223x; 1.0223x over previous
//
#include <hip/hip_runtime.h>
#include <hip/hip_bf16.h>

// GraphConv 2-hop: gather(ent[tail]*rel[type]) -> scatter-mean by head -> l2norm,
// twice, fused residual outputs.
//
// R2->R3: atomic scatter (92us, 17x write-amp) -> bucket counting sort: 360->251us.
// R4->R6: bf16 gather table: hops 74->57us. R6->R8: pair-edge hop: 57->54.3us.
// R9: cooperative grid.sync CSR: REGRESSED (275us). Reverted.
// R13: sync-free fusions (6 launches): 222.0us (best).
// R14: quad-edge hop + CHUNK 4096: REGRESSED to 225.5 (hops 52->53.7) => hop is
//      byte-bound at ~3.1 TB/s L2-miss fill; instruction width is irrelevant now.
// R15: revert to R13 exact config (measured best).
//
// Time model: ~75-80us fixed harness + 104us hops (fabric-floor random 128B gathers)
//             + ~40us CSR build. Remaining lever (fp8 table) is an accuracy gamble.
//
// ws (ints): packed[E] | unionA{staging int[E], ent1 u16[n_ent*64]} |
//            ent_bf16 u16[n_ent*64] | G[L] | Gscan[L] | bsum[128] |
//            row_start[n_ent+1] | rel1 f32[n_rel*64]
// unionA safe: staging dies at finalize; ent1 born in hop1 (after finalize).

#define CHUNK 8192
#define BSHIFT 8
#define BMASK 255
#define PREB 512   // fused-pre grid blocks

__device__ __forceinline__ float b2f(unsigned int u16bits) {
    return __uint_as_float(u16bits << 16);
}
__device__ __forceinline__ unsigned int f2b_u32(float f) {  // bf16 bits, RNE
    unsigned int u = __float_as_uint(f);
    return (u + 0x7FFFu + ((u >> 16) & 1u)) >> 16;
}

// ---- K1: blocks [0,nchunks): per-chunk bucket histogram; rest: cvt; last: +rel ----
__global__ __launch_bounds__(512) void fused_pre_kernel(
    const int* __restrict__ heads, const float* __restrict__ entity_emb,
    const float* __restrict__ relation_emb,
    int* __restrict__ G, unsigned int* __restrict__ ent_bf16,
    float* __restrict__ rel1, float* __restrict__ out_rel,
    int E, int nchunks, int nb, int n_ent, int n_rel)
{
    const int b = blockIdx.x;
    const int tid = threadIdx.x;
    if (b < nchunks) {
        __shared__ int hist[512];
        for (int i = tid; i < nb; i += 512) hist[i] = 0;
        __syncthreads();
        const int lo = b * CHUNK;
        const int hi = min(lo + CHUNK, E);
        for (int i = lo + tid; i < hi; i += 512)
            atomicAdd(&hist[heads[i] >> BSHIFT], 1);
        __syncthreads();
        for (int i = tid; i < nb; i += 512) G[i * nchunks + b] = hist[i];
    } else {
        const int lane = tid & 63;
        const int w = tid >> 6;
        if (b == PREB - 1) {
            // rel1 = l2norm(rel0); rel2 = l2norm(rel1) (= rel1); out = rel0+rel1+rel2
            for (int row = w; row < n_rel; row += 8) {
                float v = relation_emb[row * 64 + lane];
                float ss = v * v;
#pragma unroll
                for (int off = 32; off > 0; off >>= 1) ss += __shfl_xor(ss, off);
                float r1v = v / fmaxf(sqrtf(ss), 1e-12f);
                float ss2 = r1v * r1v;
#pragma unroll
                for (int off = 32; off > 0; off >>= 1) ss2 += __shfl_xor(ss2, off);
                float r2v = r1v / fmaxf(sqrtf(ss2), 1e-12f);
                rel1[row * 64 + lane] = r1v;
                out_rel[row * 64 + lane] = v + r1v + r2v;
            }
        }
        const int ncvt = PREB - nchunks;
        const int cb = b - nchunks;
        const int n4 = n_ent * 16;
        const uint4* in4 = (const uint4*)entity_emb;
        uint2* out2 = (uint2*)ent_bf16;
        for (int i = cb * 512 + tid; i < n4; i += ncvt * 512) {
            uint4 v = in4[i];
            uint2 o;
            o.x = f2b_u32(__uint_as_float(v.x)) | (f2b_u32(__uint_as_float(v.y)) << 16);
            o.y = f2b_u32(__uint_as_float(v.z)) | (f2b_u32(__uint_as_float(v.w)) << 16);
            out2[i] = o;
        }
    }
}

// ---- K2: exclusive scan of G in 1024-chunks; per-block totals to bsum ----
__global__ void scan_block(const int* __restrict__ in, int* __restrict__ out_excl,
                           int* __restrict__ blocksum, int n) {
    __shared__ int wsum[16];
    const int tid = threadIdx.x;
    const int gi = blockIdx.x * 1024 + tid;
    const int lane = tid & 63, wid = tid >> 6;
    int v = (gi < n) ? in[gi] : 0;
    int s = v;
#pragma unroll
    for (int off = 1; off < 64; off <<= 1) {
        int t = __shfl_up(s, off);
        if (lane >= off) s += t;
    }
    if (lane == 63) wsum[wid] = s;
    __syncthreads();
    if (wid == 0) {
        int ws = (lane < 16) ? wsum[lane] : 0;
#pragma unroll
        for (int off = 1; off < 16; off <<= 1) {
            int t = __shfl_up(ws, off);
            if (lane >= off) ws += t;
        }
        if (lane < 16) wsum[lane] = ws;
        if (lane == 15 && blocksum) blocksum[blockIdx.x] = ws;
    }
    __syncthreads();
    int wave_off = (wid > 0) ? wsum[wid - 1] : 0;
    if (gi < n) out_excl[gi] = s - v + wave_off;
}

// ---- K3: place edges into per-(chunk,bucket) disjoint staging ranges ----
// bsum prefix computed in-block by wave 0 (nscan<=64 entries).
__global__ __launch_bounds__(512) void place_stage_kernel(
    const int* __restrict__ heads, const int* __restrict__ tails,
    const int* __restrict__ etype, const int* __restrict__ Gscan,
    const int* __restrict__ bsum,
    int* __restrict__ staging, int E, int nchunks, int nb, int nscan)
{
    __shared__ int cur[512];
    __shared__ int pref[64];
    const int blk = blockIdx.x;
    const int tid = threadIdx.x;
    if (tid < 64) {
        int v = (tid < nscan) ? bsum[tid] : 0;
        int s = v;
#pragma unroll
        for (int off = 1; off < 64; off <<= 1) {
            int t = __shfl_up(s, off);
            if (tid >= off) s += t;
        }
        pref[tid] = s - v;   // exclusive
    }
    __syncthreads();
    for (int i = tid; i < nb; i += 512) {
        int idx = i * nchunks + blk;
        cur[i] = Gscan[idx] + pref[idx >> 10];
    }
    __syncthreads();
    const int lo = blk * CHUNK;
    const int hi = min(lo + CHUNK, E);
    for (int i = lo + tid; i < hi; i += 512) {
        int h = heads[i];
        int entry = tails[i] | (etype[i] << 17) | ((h & BMASK) << 21);
        int pos = atomicAdd(&cur[h >> BSHIFT], 1);
        staging[pos] = entry;
    }
}

// ---- K4: per-bucket degree count + scan -> row_start; final CSR placement ----
__global__ __launch_bounds__(512) void finalize_kernel(
    const int* __restrict__ staging, const int* __restrict__ Gscan,
    const int* __restrict__ bsum,
    int* __restrict__ packed, int* __restrict__ row_start,
    int E, int nchunks, int nb, int nscan, int n_ent)
{
    __shared__ int deg[256], pos[256], cur[256];
    __shared__ int pref[64];
    const int b = blockIdx.x;
    const int tid = threadIdx.x;              // 512 threads
    if (tid < 64) {
        int v = (tid < nscan) ? bsum[tid] : 0;
        int s = v;
#pragma unroll
        for (int off = 1; off < 64; off <<= 1) {
            int t = __shfl_up(s, off);
            if (tid >= off) s += t;
        }
        pref[tid] = s - v;
    }
    __syncthreads();
    const int head_lo = b << BSHIFT;
    const int i0 = b * nchunks;
    const int seg_start = Gscan[i0] + pref[i0 >> 10];
    int seg_end = E;
    if (b + 1 < nb) {
        const int i1 = (b + 1) * nchunks;
        seg_end = Gscan[i1] + pref[i1 >> 10];
    }
    if (tid < 256) deg[tid] = 0;
    __syncthreads();
    for (int i = seg_start + tid; i < seg_end; i += 512)
        atomicAdd(&deg[(staging[i] >> 21) & BMASK], 1);
    __syncthreads();
    if (tid < 256) pos[tid] = deg[tid];
    __syncthreads();
    for (int off = 1; off < 256; off <<= 1) {
        int t = (tid >= off && tid < 256) ? pos[tid - off] : 0;
        __syncthreads();
        if (tid < 256) pos[tid] += t;
        __syncthreads();
    }
    if (tid < 256) {
        const int excl = pos[tid] - deg[tid];
        const int h = head_lo + tid;
        if (h < n_ent) row_start[h] = seg_start + excl;
        cur[tid] = seg_start + excl;
    }
    if (b == 0 && tid == 0) row_start[n_ent] = E;
    __syncthreads();
    for (int i = seg_start + tid; i < seg_end; i += 512) {
        int v = staging[i];
        int p = atomicAdd(&cur[(v >> 21) & BMASK], 1);
        packed[p] = v;
    }
}

// ---- hop: one wave per row; lanes 0-31 = edge A, 32-63 = edge B; uint gathers
//      (2 bf16 channels/lane, 2 edges/wave-instruction); f32 accumulation ----
template <bool FINAL>
__global__ void hop_kernel(const unsigned int* __restrict__ ent_src,  // bf16-pair table
                           const float* __restrict__ rel_src,
                           const int* __restrict__ row_start,
                           const int* __restrict__ packed,
                           unsigned int* __restrict__ ent_next,       // FINAL=false
                           const float2* __restrict__ ent0,           // FINAL=true
                           const float2* __restrict__ drug0,          // FINAL=true
                           float2* __restrict__ out_ent,              // FINAL=true
                           float2* __restrict__ out_drug,             // FINAL=true
                           int n_rows, int n_drugs) {
    __shared__ float rel_lds[16 * 64];
    for (int i = threadIdx.x; i < 16 * 64; i += blockDim.x) rel_lds[i] = rel_src[i];
    __syncthreads();

    const int lane = threadIdx.x & 63;
    const int half = lane >> 5;
    const int c = lane & 31;
    const int wave = blockIdx.x * (blockDim.x >> 6) + (threadIdx.x >> 6);
    const int nw = gridDim.x * (blockDim.x >> 6);

    for (int r = wave; r < n_rows; r += nw) {
        const int start = row_start[r];
        const int deg = row_start[r + 1] - start;
        float a00 = 0.f, a01 = 0.f, a10 = 0.f, a11 = 0.f;
        float a20 = 0.f, a21 = 0.f, a30 = 0.f, a31 = 0.f;
        for (int base = 0; base < deg; base += 64) {
            int rem = deg - base;
            if (rem > 64) rem = 64;
            int pk = 0;
            if (lane < rem) pk = packed[start + base + lane];
            const int npairs = (rem + 1) >> 1;
            for (int i = 0; i < npairs; i += 4) {
                int e0 = 2 * (i + 0) + half;
                int e1 = 2 * (i + 1) + half;
                int e2 = 2 * (i + 2) + half;
                int e3 = 2 * (i + 3) + half;
                int p0 = __shfl(pk, e0 & 63), p1 = __shfl(pk, e1 & 63);
                int p2 = __shfl(pk, e2 & 63), p3 = __shfl(pk, e3 & 63);
                unsigned int u0 = 0, u1 = 0, u2 = 0, u3 = 0;
                if (e0 < rem) u0 = ent_src[(size_t)(p0 & 131071) * 32 + c];
                if (e1 < rem) u1 = ent_src[(size_t)(p1 & 131071) * 32 + c];
                if (e2 < rem) u2 = ent_src[(size_t)(p2 & 131071) * 32 + c];
                if (e3 < rem) u3 = ent_src[(size_t)(p3 & 131071) * 32 + c];
                const float2 r0 = *(const float2*)&rel_lds[((p0 >> 17) & 15) * 64 + 2 * c];
                const float2 r1 = *(const float2*)&rel_lds[((p1 >> 17) & 15) * 64 + 2 * c];
                const float2 r2 = *(const float2*)&rel_lds[((p2 >> 17) & 15) * 64 + 2 * c];
                const float2 r3 = *(const float2*)&rel_lds[((p3 >> 17) & 15) * 64 + 2 * c];
                a00 = fmaf(b2f(u0 & 0xFFFFu), r0.x, a00);
                a01 = fmaf(b2f(u0 >> 16), r0.y, a01);
                a10 = fmaf(b2f(u1 & 0xFFFFu), r1.x, a10);
                a11 = fmaf(b2f(u1 >> 16), r1.y, a11);
                a20 = fmaf(b2f(u2 & 0xFFFFu), r2.x, a20);
                a21 = fmaf(b2f(u2 >> 16), r2.y, a21);
                a30 = fmaf(b2f(u3 & 0xFFFFu), r3.x, a30);
                a31 = fmaf(b2f(u3 >> 16), r3.y, a31);
            }
        }
        float a0 = (a00 + a10) + (a20 + a30);
        float a1 = (a01 + a11) + (a21 + a31);
        a0 += __shfl_xor(a0, 32);
        a1 += __shfl_xor(a1, 32);
        const float denom = (float)(deg > 0 ? deg : 1);
        a0 /= denom;
        a1 /= denom;
        float ss = a0 * a0 + a1 * a1;
#pragma unroll
        for (int off = 16; off > 0; off >>= 1) ss += __shfl_xor(ss, off);
        const float inv = 1.0f / fmaxf(sqrtf(ss), 1e-12f);
        const float e2_0 = a0 * inv, e2_1 = a1 * inv;
        if (!FINAL) {
            if (half == 0)
                ent_next[(size_t)r * 32 + c] = f2b_u32(e2_0) | (f2b_u32(e2_1) << 16);
        } else {
            if (half == 0) {
                const unsigned int e1u = ent_src[(size_t)r * 32 + c];
                const float s0 = b2f(e1u & 0xFFFFu) + e2_0;
                const float s1 = b2f(e1u >> 16) + e2_1;
                const float2 base0 = ent0[(size_t)r * 32 + c];
                float2 o;
                o.x = base0.x + s0;
                o.y = base0.y + s1;
                out_ent[(size_t)r * 32 + c] = o;
                if (r < n_drugs) {
                    const float2 based = drug0[(size_t)r * 32 + c];
                    float2 od;
                    od.x = based.x + s0;
                    od.y = based.y + s1;
                    out_drug[(size_t)r * 32 + c] = od;
                }
            }
        }
    }
}

extern "C" void kernel_launch(void* const* d_in, const int* in_sizes, int n_in,
                              void* d_out, int out_size, void* d_ws, size_t ws_size,
                              hipStream_t stream) {
    const float* drug_emb = (const float*)d_in[0];
    const float* entity_emb = (const float*)d_in[1];
    const float* relation_emb = (const float*)d_in[2];
    const int* edge_index = (const int*)d_in[3];
    const int* edge_type = (const int*)d_in[4];

    const int n_drugs = in_sizes[0] / 64;   // 2000
    const int n_ent = in_sizes[1] / 64;     // 100000
    const int n_rel = in_sizes[2] / 64;     // 16
    const int E = in_sizes[4];              // 1250000

    const int* heads = edge_index;
    const int* tails = edge_index + E;

    const int nchunks = (E + CHUNK - 1) / CHUNK;          // 153
    const int nb = (n_ent + (1 << BSHIFT) - 1) >> BSHIFT; // 391
    const int L = nb * nchunks;                           // 59,823
    const int nscan = (L + 1023) / 1024;                  // 59 (<=64)

    // ws carve-up (int units).
    int* packed = (int*)d_ws;                                    // E
    int* unionA = packed + ((E + 1) & ~1);                       // staging | ent1
    int* staging = unionA;                                       // E (dies at finalize)
    unsigned int* ent1 = (unsigned int*)unionA;                  // n_ent*32 (born hop1)
    size_t unionA_ints = (size_t)n_ent * 32;                     // 3.2M >= E
    if (unionA_ints < (size_t)E) unionA_ints = (size_t)E;
    unsigned int* ent_bf16 = (unsigned int*)(unionA + unionA_ints);  // n_ent*32
    int* G = unionA + unionA_ints + (size_t)n_ent * 32;          // L
    int* Gscan = G + L;                                          // L
    int* bsum = Gscan + L;                                       // 128
    int* row_start = bsum + 128;                                 // n_ent+1
    float* rel1 = (float*)(row_start + n_ent + 1);               // n_rel*64

    float* out_ent = (float*)d_out;
    float* out_drug = out_ent + (size_t)n_ent * 64;
    float* out_rel = out_drug + (size_t)n_drugs * 64;

    fused_pre_kernel<<<PREB, 512, 0, stream>>>(heads, entity_emb, relation_emb,
                                               G, ent_bf16, rel1, out_rel,
                                               E, nchunks, nb, n_ent, n_rel);
    scan_block<<<nscan, 1024, 0, stream>>>(G, Gscan, bsum, L);
    place_stage_kernel<<<nchunks, 512, 0, stream>>>(heads, tails, edge_type, Gscan,
                                                    bsum, staging, E, nchunks, nb, nscan);
    finalize_kernel<<<nb, 512, 0, stream>>>(staging, Gscan, bsum, packed, row_start,
                                            E, nchunks, nb, nscan, n_ent);
    hop_kernel<false><<<2048, 256, 0, stream>>>(ent_bf16, relation_emb, row_start, packed,
                                                ent1, nullptr, nullptr, nullptr, nullptr,
                                                n_ent, 0);
    hop_kernel<true><<<2048, 256, 0, stream>>>(ent1, rel1, row_start, packed,
                                               nullptr, (const float2*)entity_emb,
                                               (const float2*)drug_emb,
                                               (float2*)out_ent, (float2*)out_drug,
                                               n_ent, n_drugs);
}